// Round 2
// baseline (231.251 us; speedup 1.0000x reference)
//
#include <hip/hip_runtime.h>

#define BATCH 32
#define SEQ 512
#define CH4 96            // float4 per channel row (384 ch)
#define MAXL 4096
#define THREADS 256
#define SLABS 64          // blocks per batch; each owns 64 output rows
#define ROWS_PB 64        // MAXL / SLABS
#define ITERS 24          // ROWS_PB*CH4 / THREADS

typedef float v4f __attribute__((ext_vector_type(4)));
typedef int   v4i __attribute__((ext_vector_type(4)));

// Output-parallel gather formulation (R8 = R7 + binary-search fix).
// R7 bug: 9-step search over range [0,512] (513 outcomes) can leave a
// 1-wide bracket -> source frame off by one -> absmax 5.8. Fixed: 10
// steps = ceil(log2(513)); converged lanes are stable under extra steps.
//
// Structure (R7 theory, unfalsified):
//   grid = 32 batches x 64 slabs = 2048 blocks x 256 threads
//   1. wave0: shfl scan of the batch's 512 durations -> s_end (R6-proven)
//   2. wave0: per output row t in slab, 10-step branchless binary search
//      for src frame (searchsorted right); t>=total -> -1. Mask written here.
//   3. all 256 lanes stream: 24 iters x (16B gather load, 16B contiguous
//      store). Tail rows (j==-1) store zero -- no separate tail pass.
// Mirrors the 6.6 TB/s fill shape: every lane stores every iter, uniform
// per-block work, 100% occupancy. x re-reads hit L2/L3 (25 MB total).
__global__ __launch_bounds__(THREADS) void lr_gather(
    const v4f* __restrict__ x,
    const v4i* __restrict__ dur4,
    const int* __restrict__ max_len_p,
    v4f* __restrict__ out,
    float* __restrict__ out_mask)
{
    __shared__ int s_end[SEQ];
    __shared__ int s_src[ROWS_PB];

    const int tid  = threadIdx.x;
    const int bid  = blockIdx.x;
    const int b    = bid >> 6;             // SLABS = 64
    const int slab = bid & (SLABS - 1);
    const int r0   = slab * ROWS_PB;

    // --- 1. wave-0 scan: 512 durations -> clipped inclusive ends (R6-proven) ---
    if (tid < 64) {
        const v4i* dp = dur4 + b * (SEQ / 4) + tid * 2;   // 8 ints/lane
        v4i d0 = dp[0], d1 = dp[1];
        int lane_sum = d0.x + d0.y + d0.z + d0.w + d1.x + d1.y + d1.z + d1.w;
        int incl = lane_sum;
        #pragma unroll
        for (int off = 1; off < 64; off <<= 1) {
            int v = __shfl_up(incl, off, 64);
            if (tid >= off) incl += v;
        }
        int cum = incl - lane_sum;                        // exclusive prefix
        const int maxlen = max_len_p[0];
        const int base = tid * 8;
        cum += d0.x; s_end[base + 0] = min(cum, maxlen);
        cum += d0.y; s_end[base + 1] = min(cum, maxlen);
        cum += d0.z; s_end[base + 2] = min(cum, maxlen);
        cum += d0.w; s_end[base + 3] = min(cum, maxlen);
        cum += d1.x; s_end[base + 4] = min(cum, maxlen);
        cum += d1.y; s_end[base + 5] = min(cum, maxlen);
        cum += d1.z; s_end[base + 6] = min(cum, maxlen);
        cum += d1.w; s_end[base + 7] = min(cum, maxlen);
    }
    __syncthreads();

    const int total = s_end[SEQ - 1];

    // --- 2. source-frame map for this slab's 64 rows + mask write ---
    if (tid < ROWS_PB) {
        const int t = r0 + tid;
        // searchsorted(ends, t, side='right'): first j with ends[j] > t.
        // 10 steps = ceil(log2(513)) covers outcomes 0..512; branchless.
        // min(mid,511) guards the lo==hi==512 state (t>=total lanes, unused).
        int lo = 0, hi = SEQ;
        #pragma unroll
        for (int s = 0; s < 10; ++s) {
            int mid = (lo + hi) >> 1;
            mid = min(mid, SEQ - 1);
            const bool le = (s_end[mid] <= t);
            lo = le ? mid + 1 : lo;
            hi = le ? hi : mid;
        }
        s_src[tid] = (t < total) ? lo : -1;   // lo <= 511 whenever t < total
        out_mask[(b << 12) + t] = (t >= total) ? 1.0f : 0.0f;
    }
    __syncthreads();

    // --- 3. uniform gather-stream: every lane stores 16B per iteration ---
    const v4f* xb = x + (size_t)b * (SEQ * CH4);
    v4f* ob = out + ((size_t)(b << 12) + r0) * CH4;
    const v4f vzero = (v4f){0.f, 0.f, 0.f, 0.f};

    #pragma unroll 6
    for (int it = 0; it < ITERS; ++it) {
        const int g = it * THREADS + tid;     // flat f4 index within slab
        const int r = g / CH4;                // compiler magic-mul
        const int c = g - r * CH4;
        const int j = s_src[r];               // <=2 addrs per wave: broadcast
        v4f v = vzero;
        if (j >= 0) v = xb[j * CH4 + c];
        ob[g] = v;                            // 256 lanes x 16B contiguous
    }
}

extern "C" void kernel_launch(void* const* d_in, const int* in_sizes, int n_in,
                              void* d_out, int out_size, void* d_ws, size_t ws_size,
                              hipStream_t stream) {
    const v4f* x = (const v4f*)d_in[0];
    const v4i* dur4 = (const v4i*)d_in[1];
    const int* max_len_p = (const int*)d_in[2];
    float* out = (float*)d_out;
    float* out_mask = out + (size_t)BATCH * MAXL * CH4 * 4;

    lr_gather<<<BATCH * SLABS, THREADS, 0, stream>>>(
        x, dur4, max_len_p, (v4f*)out, out_mask);
}